// Round 1
// baseline (146.437 us; speedup 1.0000x reference)
//
#include <hip/hip_runtime.h>
#include <cstdint>

typedef short short8 __attribute__((ext_vector_type(8)));
typedef short short4_t __attribute__((ext_vector_type(4)));
typedef float floatx4 __attribute__((ext_vector_type(4)));

#define MFMA_BF16 __builtin_amdgcn_mfma_f32_16x16x32_bf16

// round-to-nearest-even fp32 -> bf16 (bits in a short)
__device__ __forceinline__ short f2bf(float f) {
  union { float f; unsigned u; } a; a.f = f;
  unsigned r = a.u + 0x7FFFu + ((a.u >> 16) & 1u);
  return (short)(r >> 16);
}
__device__ __forceinline__ float bf2f(short s) {
  union { unsigned u; float f; } a;
  a.u = ((unsigned)(unsigned short)s) << 16;
  return a.f;
}
__device__ __forceinline__ float silu_f(float v) {
  return v / (1.0f + __expf(-v));
}

#define QDIM 256
#define DEMB 64
#define TILE_T 32
#define ITERS 4          // tokens per block = 128
#define NBLK1 512        // 2 blocks/CU
#define YSTR 264         // shorts; 528 B rows
#define TSTR 40          // UVT t-stride in shorts; 80 B rows
#define HSTR 72          // shorts; 144 B rows

// output layout (floats)
#define OFF_QKV 4194304
#define OFF_SW  4243456
#define OFF_WO  4276224

// ws layout (floats):
//   [0, 65536)        ao partial copies (16 x 4096)
//   [65536, 65542)    sums (3 matrices x {s1, s2})
//   [65543]           wave-completion counter (unsigned)
#define AO_COPIES 16
#define WS_SUMS   65536

// ============================ K1: streaming ============================
// 2-barrier pipelined loop; all global loads issued at region start and
// covered by the region's compute before the barrier drain.
// Weight fragments are built directly from global w_sw/w_out (131 KB,
// L2-resident) -- the former k0 pack kernel is fused away; its loads and
// f2bf conversions overlap the tile-0 y staging latency.
__global__ __launch_bounds__(256, 2) void k1_main(
    const float* __restrict__ x, const float* __restrict__ y,
    const float* __restrict__ w_sw, const float* __restrict__ w_out,
    float* __restrict__ y_out, float* __restrict__ ao_copies)
{
  __shared__ __align__(16) short Ylds[2][TILE_T * YSTR];  // 2 x 16896 B
  __shared__ __align__(16) short UVT[128 * TSTR];         // 10240 B
  __shared__ __align__(16) short Hlds[TILE_T * HSTR];     //  4608 B

  const int tid  = threadIdx.x;
  const int lane = tid & 63;
  const int wave = tid >> 6;
  const int l15  = lane & 15;
  const int quad = lane >> 4;
  const floatx4 fzero = {0.f, 0.f, 0.f, 0.f};
  const int tok0 = blockIdx.x * (TILE_T * ITERS);

  // ---- stage tile 0: issue y global loads FIRST (longest latency) ----
  float4 yreg[8];
  {
    const float4* src = (const float4*)(y + (size_t)tok0 * QDIM);
#pragma unroll
    for (int rep = 0; rep < 8; ++rep) yreg[rep] = src[tid + rep * 256];
  }

  // ---- weight fragments direct from global (covers y latency) ----
  // b1[nt][kt] = bf16(w_sw[wave*32 + nt*16 + l15][kt*32 + quad*8 + 0..7])
  short8 b1[2][8];
#pragma unroll
  for (int nt = 0; nt < 2; ++nt) {
    const float* wr = w_sw + (size_t)(wave * 32 + nt * 16 + l15) * QDIM + quad * 8;
#pragma unroll
    for (int kt = 0; kt < 8; ++kt) {
      float4 f0 = *(const float4*)(wr + kt * 32);
      float4 f1 = *(const float4*)(wr + kt * 32 + 4);
      short8 f = { f2bf(f0.x), f2bf(f0.y), f2bf(f0.z), f2bf(f0.w),
                   f2bf(f1.x), f2bf(f1.y), f2bf(f1.z), f2bf(f1.w) };
      b1[nt][kt] = f;
    }
  }
  // b2[kt] = bf16(w_out[wave*16 + l15][kt*32 + quad*8 + 0..7])
  short8 b2[2];
#pragma unroll
  for (int kt = 0; kt < 2; ++kt) {
    const float* wr = w_out + (size_t)(wave * 16 + l15) * DEMB + kt * 32 + quad * 8;
    float4 f0 = *(const float4*)(wr);
    float4 f1 = *(const float4*)(wr + 4);
    short8 f = { f2bf(f0.x), f2bf(f0.y), f2bf(f0.z), f2bf(f0.w),
                 f2bf(f1.x), f2bf(f1.y), f2bf(f1.z), f2bf(f1.w) };
    b2[kt] = f;
  }

  floatx4 ao_acc[4];
#pragma unroll
  for (int i = 0; i < 4; ++i) ao_acc[i] = fzero;

  // ---- pack tile 0 into LDS ----
  {
#pragma unroll
    for (int rep = 0; rep < 8; ++rep) {
      int i = tid + rep * 256;
      int tok = i >> 6;
      int col = (i & 63) * 4;
      float4 f = yreg[rep];
      short4_t p4 = { f2bf(f.x), f2bf(f.y), f2bf(f.z), f2bf(f.w) };
      *(short4_t*)&Ylds[0][tok * YSTR + col] = p4;
    }
  }
  float xreg[8];
  __syncthreads();   // barrier A (enter it=0)

  for (int it = 0; it < ITERS; ++it) {
    const int cur = it & 1;

    // ================= region RX =================
    // issue next y tile loads first (longest latency, covered by RX compute)
    if (it + 1 < ITERS) {
      const float4* src = (const float4*)(y + (size_t)(tok0 + (it + 1) * TILE_T) * QDIM);
#pragma unroll
      for (int rep = 0; rep < 8; ++rep) yreg[rep] = src[tid + rep * 256];
    }
    // epilogue of previous tile: y_out = x + H @ Wout^T
    if (it > 0) {
      const int tb = tok0 + (it - 1) * TILE_T;
#pragma unroll
      for (int mt = 0; mt < 2; ++mt) {
        floatx4 acc2 = fzero;
#pragma unroll
        for (int kt = 0; kt < 2; ++kt) {
          short8 a2 = *(const short8*)&Hlds[(mt * 16 + l15) * HSTR + kt * 32 + quad * 8];
          acc2 = MFMA_BF16(a2, b2[kt], acc2, 0, 0, 0);
        }
        int e = wave * 16 + l15;
#pragma unroll
        for (int r = 0; r < 4; ++r) {
          size_t idx = (size_t)(tb + mt * 16 + quad * 4 + r) * DEMB + e;
          y_out[idx] = xreg[mt * 4 + r] + acc2[r];
        }
      }
    }
    // UV = Ytile @ Wsw^T
    floatx4 acc[2][2];
#pragma unroll
    for (int a = 0; a < 2; ++a)
#pragma unroll
      for (int b = 0; b < 2; ++b) acc[a][b] = fzero;
#pragma unroll
    for (int kt = 0; kt < 8; ++kt) {
      short8 a0 = *(const short8*)&Ylds[cur][(l15)      * YSTR + kt * 32 + quad * 8];
      short8 a1 = *(const short8*)&Ylds[cur][(16 + l15) * YSTR + kt * 32 + quad * 8];
      acc[0][0] = MFMA_BF16(a0, b1[0][kt], acc[0][0], 0, 0, 0);
      acc[0][1] = MFMA_BF16(a0, b1[1][kt], acc[0][1], 0, 0, 0);
      acc[1][0] = MFMA_BF16(a1, b1[0][kt], acc[1][0], 0, 0, 0);
      acc[1][1] = MFMA_BF16(a1, b1[1][kt], acc[1][1], 0, 0, 0);
    }
    // writeback as bf16 UV^T[c][t]: packed b64
#pragma unroll
    for (int mt = 0; mt < 2; ++mt)
#pragma unroll
      for (int nt = 0; nt < 2; ++nt) {
        short4_t p4;
#pragma unroll
        for (int r = 0; r < 4; ++r) p4[r] = f2bf(acc[mt][nt][r]);
        int c  = wave * 32 + nt * 16 + l15;
        int t0 = mt * 16 + quad * 4;
        *(short4_t*)&UVT[c * TSTR + t0] = p4;
      }
    __syncthreads();   // barrier B

    // ================= region RY =================
    // issue x loads for THIS tile (used in next RX's epilogue)
    {
      const float* xb = x + (size_t)(tok0 + it * TILE_T) * DEMB + wave * 16 + l15;
#pragma unroll
      for (int mt = 0; mt < 2; ++mt)
#pragma unroll
        for (int r = 0; r < 4; ++r)
          xreg[mt * 4 + r] = xb[(mt * 16 + quad * 4 + r) * DEMB];
    }
    // h = u * silu(v) -> Hlds
    {
      int d  = tid & 63;
      int t0 = (tid >> 6) * 8;
      short8 u8 = *(const short8*)&UVT[d * TSTR + t0];
      short8 v8 = *(const short8*)&UVT[(64 + d) * TSTR + t0];
#pragma unroll
      for (int j = 0; j < 8; ++j) {
        float h = bf2f(u8[j]) * silu_f(bf2f(v8[j]));
        Hlds[(t0 + j) * HSTR + d] = f2bf(h);
      }
    }
    // ao += u^T v
    {
      short8 a3 = *(const short8*)&UVT[(wave * 16 + l15) * TSTR + quad * 8];
#pragma unroll
      for (int et = 0; et < 4; ++et) {
        short8 b3 = *(const short8*)&UVT[(64 + et * 16 + l15) * TSTR + quad * 8];
        ao_acc[et] = MFMA_BF16(a3, b3, ao_acc[et], 0, 0, 0);
      }
    }
    // pack prefetched y -> other Y buffer
    if (it + 1 < ITERS) {
#pragma unroll
      for (int rep = 0; rep < 8; ++rep) {
        int i = tid + rep * 256;
        int tok = i >> 6;
        int col = (i & 63) * 4;
        float4 f = yreg[rep];
        short4_t p4 = { f2bf(f.x), f2bf(f.y), f2bf(f.z), f2bf(f.w) };
        *(short4_t*)&Ylds[1 - cur][tok * YSTR + col] = p4;
      }
    }
    __syncthreads();   // barrier A (next iter)
  }

  // ---- final epilogue (tile ITERS-1) ----
  {
    const int tb = tok0 + (ITERS - 1) * TILE_T;
#pragma unroll
    for (int mt = 0; mt < 2; ++mt) {
      floatx4 acc2 = fzero;
#pragma unroll
      for (int kt = 0; kt < 2; ++kt) {
        short8 a2 = *(const short8*)&Hlds[(mt * 16 + l15) * HSTR + kt * 32 + quad * 8];
        acc2 = MFMA_BF16(a2, b2[kt], acc2, 0, 0, 0);
      }
      int e = wave * 16 + l15;
#pragma unroll
      for (int r = 0; r < 4; ++r) {
        size_t idx = (size_t)(tb + mt * 16 + quad * 4 + r) * DEMB + e;
        y_out[idx] = xreg[mt * 4 + r] + acc2[r];
      }
    }
  }

  // ---- flush ao partials ----
  float* dst = ao_copies + (blockIdx.x & (AO_COPIES - 1)) * 4096;
#pragma unroll
  for (int et = 0; et < 4; ++et)
#pragma unroll
    for (int r = 0; r < 4; ++r) {
      int d = wave * 16 + quad * 4 + r;
      int e = et * 16 + l15;
      atomicAdd(&dst[d * 64 + e], ao_acc[et][r]);
    }
}

// ========== K3 fused: ao finalize + weight updates + final scale =======
// 21 blocks x 256 threads (4 waves = 4 rids each; 84 rids total).
// Phase 0: every block redundantly reduces ao_copies (262 KB, L2-hot) and
//          builds the rms-normed aoT in LDS -- replaces the old 1-block k2.
// Phase 1: per-wave k3 update-candidate GEMMs; vals held in registers.
// Phase 2: 84-wave device-scope counter barrier (21 blocks trivially
//          co-resident), then each wave reads the global sums and writes
//          its own vals * scale -- replaces the old k4 launch. The only
//          cross-block data are atomics (sums, cnt): XCD-coherence safe.
__global__ __launch_bounds__(256) void k3_fused(
    const float* __restrict__ w_qkv, const float* __restrict__ w_sw,
    const float* __restrict__ w_out, const float* __restrict__ out_w,
    const float* __restrict__ ao_copies, const float* __restrict__ tao,
    float* __restrict__ out, float* __restrict__ sums,
    unsigned* __restrict__ cnt)
{
  __shared__ float aoFT[64 * 65];   // [e][d], pad 65
  __shared__ float ssPart[256];
  __shared__ float scRow[64];
  __shared__ __align__(16) short Nlds[4][16 * 72];
  const int tid = threadIdx.x;

  // ---- phase 0: finalize ao (redundant per block, parallel across 21) ----
#pragma unroll
  for (int k = 0; k < 16; ++k) {
    int idx = k * 256 + tid;          // = d*64 + e, coalesced
    float v = 0.f;
#pragma unroll
    for (int c = 0; c < AO_COPIES; ++c) v += ao_copies[c * 4096 + idx];
    v *= (1.0f / 64.0f);              // /B * n_embd^-0.5
    int d = idx >> 6, e = idx & 63;
    aoFT[e * 65 + d] = v;
  }
  __syncthreads();
  {
    int d = tid >> 2, q = tid & 3;
    float ssp = 0.f;
#pragma unroll
    for (int e2 = 0; e2 < 16; ++e2) {
      float v = aoFT[(q * 16 + e2) * 65 + d];
      ssp += v * v;
    }
    ssPart[tid] = ssp;
  }
  __syncthreads();
  if (tid < 64) {
    float ss = ssPart[tid * 4] + ssPart[tid * 4 + 1] +
               ssPart[tid * 4 + 2] + ssPart[tid * 4 + 3];
    scRow[tid] = rsqrtf(ss * (1.0f / 64.0f) + 1.1920929e-07f);
  }
  __syncthreads();

  const int lane = tid & 63;
  const int wave = tid >> 6;
  const int l15  = lane & 15;
  const int quad = lane >> 4;
  const int rid  = blockIdx.x * 4 + wave;   // [0, 84)
  const floatx4 fzero = {0.f, 0.f, 0.f, 0.f};

  // bf[kt][nt] lanewise: e = nt*16+l15, d = kt*32+quad*8+j (matches old aoT)
  short8 bf[2][4];
#pragma unroll
  for (int kt = 0; kt < 2; ++kt)
#pragma unroll
    for (int nt = 0; nt < 4; ++nt) {
      short8 f;
#pragma unroll
      for (int j = 0; j < 8; ++j) {
        int d = kt * 32 + quad * 8 + j;
        f[j] = f2bf(aoFT[(nt * 16 + l15) * 65 + d] * scRow[d]);
      }
      bf[kt][nt] = f;
    }

  short8 af[2];
  if (rid < 48) {
    const float* wr = w_qkv + (size_t)(rid * 16 + l15) * 64;
#pragma unroll
    for (int kt = 0; kt < 2; ++kt) {
      const float* p = wr + kt * 32 + quad * 8;
      short8 f;
#pragma unroll
      for (int j = 0; j < 8; ++j) f[j] = f2bf(p[j]);
      af[kt] = f;
    }
  } else if (rid < 80) {
    int p0 = (rid - 48) * 16;
#pragma unroll
    for (int kt = 0; kt < 2; ++kt) {
      short8 f;
#pragma unroll
      for (int j = 0; j < 8; ++j) {
        int a = kt * 32 + quad * 8 + j;
        f[j] = f2bf(w_sw[a * 512 + p0 + l15]);
      }
      af[kt] = f;
    }
  } else {
    const float* wr = w_out + (size_t)((rid - 80) * 16 + l15) * 64;
#pragma unroll
    for (int kt = 0; kt < 2; ++kt) {
      const float* p = wr + kt * 32 + quad * 8;
      short8 f;
#pragma unroll
      for (int j = 0; j < 8; ++j) f[j] = f2bf(p[j]);
      af[kt] = f;
    }
  }

  floatx4 acc[4];
#pragma unroll
  for (int nt = 0; nt < 4; ++nt) acc[nt] = fzero;
#pragma unroll
  for (int kt = 0; kt < 2; ++kt)
#pragma unroll
    for (int nt = 0; nt < 4; ++nt)
      acc[nt] = MFMA_BF16(af[kt], bf[kt][nt], acc[nt], 0, 0, 0);
#pragma unroll
  for (int nt = 0; nt < 4; ++nt)
#pragma unroll
    for (int r = 0; r < 4; ++r)
      Nlds[wave][(quad * 4 + r) * 72 + nt * 16 + l15] = f2bf(silu_f(acc[nt][r]));
  __syncthreads();

  float s1 = 0.f, s2 = 0.f;
  int matrix;
  float vals[16];

  if (rid < 48 || rid >= 80) {
    matrix = (rid < 48) ? 0 : 2;
    short8 a2[2];
#pragma unroll
    for (int kt = 0; kt < 2; ++kt)
      a2[kt] = *(const short8*)&Nlds[wave][l15 * 72 + kt * 32 + quad * 8];
    short8 b2w[2][4];
#pragma unroll
    for (int nt = 0; nt < 4; ++nt) {
      const float* wr = out_w + (size_t)(nt * 16 + l15) * 64;
#pragma unroll
      for (int kt = 0; kt < 2; ++kt) {
        const float* p = wr + kt * 32 + quad * 8;
        short8 f;
#pragma unroll
        for (int j = 0; j < 8; ++j) f[j] = f2bf(p[j]);
        b2w[kt][nt] = f;
      }
    }
    floatx4 acc2[4];
#pragma unroll
    for (int nt = 0; nt < 4; ++nt) acc2[nt] = fzero;
#pragma unroll
    for (int kt = 0; kt < 2; ++kt)
#pragma unroll
      for (int nt = 0; nt < 4; ++nt)
        acc2[nt] = MFMA_BF16(a2[kt], b2w[kt][nt], acc2[nt], 0, 0, 0);

    const float* Wsrc = (rid < 48) ? w_qkv : w_out;
    int base_row = (rid < 48) ? rid * 16 : (rid - 80) * 16;
#pragma unroll
    for (int nt = 0; nt < 4; ++nt)
#pragma unroll
      for (int r = 0; r < 4; ++r) {
        int row = base_row + quad * 4 + r;
        int col = nt * 16 + l15;
        float val = Wsrc[row * 64 + col] + acc2[nt][r];
        vals[nt * 4 + r] = val;
        s1 += val; s2 += val * val;
      }
  } else {
    matrix = 1;
    int p0 = (rid - 48) * 16;
    short8 b2s[2];
#pragma unroll
    for (int kt = 0; kt < 2; ++kt)
      b2s[kt] = *(const short8*)&Nlds[wave][l15 * 72 + kt * 32 + quad * 8];
    short8 a2w[4][2];
#pragma unroll
    for (int mt = 0; mt < 4; ++mt) {
      const float* wr = out_w + (size_t)(mt * 16 + l15) * 64;
#pragma unroll
      for (int kt = 0; kt < 2; ++kt) {
        const float* p = wr + kt * 32 + quad * 8;
        short8 f;
#pragma unroll
        for (int j = 0; j < 8; ++j) f[j] = f2bf(p[j]);
        a2w[mt][kt] = f;
      }
    }
    floatx4 acc2[4];
#pragma unroll
    for (int mt = 0; mt < 4; ++mt) acc2[mt] = fzero;
#pragma unroll
    for (int mt = 0; mt < 4; ++mt)
#pragma unroll
      for (int kt = 0; kt < 2; ++kt)
        acc2[mt] = MFMA_BF16(a2w[mt][kt], b2s[kt], acc2[mt], 0, 0, 0);
#pragma unroll
    for (int mt = 0; mt < 4; ++mt)
#pragma unroll
      for (int r = 0; r < 4; ++r) {
        int a = mt * 16 + quad * 4 + r;
        float val = w_sw[a * 512 + p0 + l15] + acc2[mt][r];
        vals[mt * 4 + r] = val;
        s1 += val; s2 += val * val;
      }
  }

#pragma unroll
  for (int off = 32; off > 0; off >>= 1) {
    s1 += __shfl_down(s1, off);
    s2 += __shfl_down(s2, off);
  }
  if (lane == 0) {
    atomicAdd(&sums[matrix * 2],     s1);
    atomicAdd(&sums[matrix * 2 + 1], s2);
    // release-publish this wave's contribution
    __hip_atomic_fetch_add(cnt, 1u, __ATOMIC_RELEASE, __HIP_MEMORY_SCOPE_AGENT);
  }
  // all lanes spin until all 84 waves have published (acquire orders the
  // subsequent sums loads); 21 blocks on 256 CUs are always co-resident
  while (__hip_atomic_load(cnt, __ATOMIC_ACQUIRE, __HIP_MEMORY_SCOPE_AGENT) < 84u) {
    __builtin_amdgcn_s_sleep(1);
  }

  float ssum = __hip_atomic_load(&sums[matrix * 2],
                                 __ATOMIC_RELAXED, __HIP_MEMORY_SCOPE_AGENT);
  float ssq  = __hip_atomic_load(&sums[matrix * 2 + 1],
                                 __ATOMIC_RELAXED, __HIP_MEMORY_SCOPE_AGENT);
  float N    = (matrix == 0) ? 49152.f : (matrix == 1) ? 32768.f : 4096.f;
  float tstd = (matrix == 0) ? 0.125f : 0.0625f;
  float mean = ssum / N;
  float var  = (ssq - N * mean * mean) / (N - 1.f);
  float sd   = sqrtf(fmaxf(var, 0.f));
  float g    = fminf(fmaxf(fabsf(tao[matrix]), 1e-8f), 1.0f);
  float scale = g * tstd / (sd + 1e-8f);

  if (rid < 48 || rid >= 80) {
    int base_row = (rid < 48) ? rid * 16 : (rid - 80) * 16;
    int off2     = (rid < 48) ? OFF_QKV : OFF_WO;
#pragma unroll
    for (int nt = 0; nt < 4; ++nt)
#pragma unroll
      for (int r = 0; r < 4; ++r) {
        int row = base_row + quad * 4 + r;
        int col = nt * 16 + l15;
        out[off2 + row * 64 + col] = vals[nt * 4 + r] * scale;
      }
  } else {
    int p0 = (rid - 48) * 16;
#pragma unroll
    for (int mt = 0; mt < 4; ++mt)
#pragma unroll
      for (int r = 0; r < 4; ++r) {
        int a = mt * 16 + quad * 4 + r;
        out[OFF_SW + a * 512 + p0 + l15] = vals[mt * 4 + r] * scale;
      }
  }
}

extern "C" void kernel_launch(void* const* d_in, const int* in_sizes, int n_in,
                              void* d_out, int out_size, void* d_ws, size_t ws_size,
                              hipStream_t stream) {
  const float* x     = (const float*)d_in[0];
  const float* y     = (const float*)d_in[1];
  const float* w_qkv = (const float*)d_in[2];
  const float* w_sw  = (const float*)d_in[3];
  const float* w_out = (const float*)d_in[4];
  const float* out_w = (const float*)d_in[5];
  const float* tao   = (const float*)d_in[6];
  float* out = (float*)d_out;
  float* ws  = (float*)d_ws;

  float* ao_copies = ws;
  float* sums      = ws + WS_SUMS;
  unsigned* cnt    = (unsigned*)(ws + WS_SUMS + 7);

  hipMemsetAsync(d_ws, 0, (WS_SUMS + 8) * sizeof(float), stream);
  k1_main<<<dim3(NBLK1), dim3(256), 0, stream>>>(x, y, w_sw, w_out, out, ao_copies);
  k3_fused<<<dim3(21), dim3(256), 0, stream>>>(w_qkv, w_sw, w_out, out_w,
                                               ao_copies, tao, out, sums, cnt);
}

// Round 2
// 144.625 us; speedup vs baseline: 1.0125x; 1.0125x over previous
//
#include <hip/hip_runtime.h>
#include <cstdint>

typedef short short8 __attribute__((ext_vector_type(8)));
typedef short short4_t __attribute__((ext_vector_type(4)));
typedef float floatx4 __attribute__((ext_vector_type(4)));

#define MFMA_BF16 __builtin_amdgcn_mfma_f32_16x16x32_bf16

// round-to-nearest-even fp32 -> bf16 (bits in a short)
__device__ __forceinline__ short f2bf(float f) {
  union { float f; unsigned u; } a; a.f = f;
  unsigned r = a.u + 0x7FFFu + ((a.u >> 16) & 1u);
  return (short)(r >> 16);
}
__device__ __forceinline__ float bf2f(short s) {
  union { unsigned u; float f; } a;
  a.u = ((unsigned)(unsigned short)s) << 16;
  return a.f;
}
__device__ __forceinline__ float silu_f(float v) {
  return v / (1.0f + __expf(-v));
}

#define QDIM 256
#define DEMB 64
#define TILE_T 32
#define ITERS 4          // tokens per block = 128
#define NBLK1 512        // 2 blocks/CU (512-thread blocks)
#define YSTR 264         // shorts; 528 B rows
#define TSTR 40          // UVT t-stride in shorts; 80 B rows
#define HSTR 72          // shorts; 144 B rows

// output layout (floats)
#define OFF_QKV 4194304
#define OFF_SW  4243456
#define OFF_WO  4276224

// ws layout (floats):
//   [0, 65536)        ao partial copies (16 x 4096)
//   [65536, 65542)    sums (3 matrices x {s1, s2})
//   [65543]           wave-completion counter (unsigned)
#define AO_COPIES 16
#define WS_SUMS   65536

// ============================ K1: streaming ============================
// 8-wave (512-thread) blocks: per-wave state halved vs the 4-wave version
// (b1 = 32 VGPR instead of 64) so __launch_bounds__(512,4) holds
// 2 blocks/CU = 16 waves/CU = 4 waves/SIMD -- 2x the latency hiding of the
// previous (256,2) layout for this BW-bound stream. Same tiles, same math.
// Wave w: owns w_sw rows [w*16, w*16+16) for UV; epilogue sub-tile
// (mt = w&1 token-block, eb = w>>1 e-block); ao sub-tiles
// (db = w>>1 d-block, et = (w&1)*2 + {0,1}).
__global__ __launch_bounds__(512, 4) void k1_main(
    const float* __restrict__ x, const float* __restrict__ y,
    const float* __restrict__ w_sw, const float* __restrict__ w_out,
    float* __restrict__ y_out, float* __restrict__ ao_copies)
{
  __shared__ __align__(16) short Ylds[2][TILE_T * YSTR];  // 2 x 16896 B
  __shared__ __align__(16) short UVT[128 * TSTR];         // 10240 B
  __shared__ __align__(16) short Hlds[TILE_T * HSTR];     //  4608 B

  const int tid  = threadIdx.x;
  const int lane = tid & 63;
  const int wave = tid >> 6;         // 0..7
  const int l15  = lane & 15;
  const int quad = lane >> 4;
  const int mt   = wave & 1;         // epilogue token-block
  const int eb   = wave >> 1;        // epilogue e-block
  const int db   = wave >> 1;        // ao d-block
  const int e0   = (wave & 1) * 2;   // ao first e-tile
  const floatx4 fzero = {0.f, 0.f, 0.f, 0.f};
  const int tok0 = blockIdx.x * (TILE_T * ITERS);

  // ---- stage tile 0: issue y global loads FIRST (longest latency) ----
  float4 yreg[4];
  {
    const float4* src = (const float4*)(y + (size_t)tok0 * QDIM);
#pragma unroll
    for (int rep = 0; rep < 4; ++rep) yreg[rep] = src[tid + rep * 512];
  }

  // ---- weight fragments direct from global (covers y latency) ----
  // b1[kt] = bf16(w_sw[wave*16 + l15][kt*32 + quad*8 + 0..7])
  short8 b1[8];
  {
    const float* wr = w_sw + (size_t)(wave * 16 + l15) * QDIM + quad * 8;
#pragma unroll
    for (int kt = 0; kt < 8; ++kt) {
      float4 f0 = *(const float4*)(wr + kt * 32);
      float4 f1 = *(const float4*)(wr + kt * 32 + 4);
      short8 f = { f2bf(f0.x), f2bf(f0.y), f2bf(f0.z), f2bf(f0.w),
                   f2bf(f1.x), f2bf(f1.y), f2bf(f1.z), f2bf(f1.w) };
      b1[kt] = f;
    }
  }
  // b2[kt] = bf16(w_out[eb*16 + l15][kt*32 + quad*8 + 0..7])
  short8 b2[2];
#pragma unroll
  for (int kt = 0; kt < 2; ++kt) {
    const float* wr = w_out + (size_t)(eb * 16 + l15) * DEMB + kt * 32 + quad * 8;
    float4 f0 = *(const float4*)(wr);
    float4 f1 = *(const float4*)(wr + 4);
    short8 f = { f2bf(f0.x), f2bf(f0.y), f2bf(f0.z), f2bf(f0.w),
                 f2bf(f1.x), f2bf(f1.y), f2bf(f1.z), f2bf(f1.w) };
    b2[kt] = f;
  }

  floatx4 ao_acc[2];
  ao_acc[0] = fzero; ao_acc[1] = fzero;

  // ---- pack tile 0 into LDS ----
  {
#pragma unroll
    for (int rep = 0; rep < 4; ++rep) {
      int i = tid + rep * 512;
      int tok = i >> 6;
      int col = (i & 63) * 4;
      float4 f = yreg[rep];
      short4_t p4 = { f2bf(f.x), f2bf(f.y), f2bf(f.z), f2bf(f.w) };
      *(short4_t*)&Ylds[0][tok * YSTR + col] = p4;
    }
  }
  float xreg[4];
  __syncthreads();   // barrier A (enter it=0)

  for (int it = 0; it < ITERS; ++it) {
    const int cur = it & 1;

    // ================= region RX =================
    // issue next y tile loads first (longest latency, covered by RX compute)
    if (it + 1 < ITERS) {
      const float4* src = (const float4*)(y + (size_t)(tok0 + (it + 1) * TILE_T) * QDIM);
#pragma unroll
      for (int rep = 0; rep < 4; ++rep) yreg[rep] = src[tid + rep * 512];
    }
    // epilogue of previous tile: y_out = x + H @ Wout^T  (one 16x16/wave)
    if (it > 0) {
      const int tb = tok0 + (it - 1) * TILE_T;
      floatx4 acc2 = fzero;
#pragma unroll
      for (int kt = 0; kt < 2; ++kt) {
        short8 a2 = *(const short8*)&Hlds[(mt * 16 + l15) * HSTR + kt * 32 + quad * 8];
        acc2 = MFMA_BF16(a2, b2[kt], acc2, 0, 0, 0);
      }
      int e = eb * 16 + l15;
#pragma unroll
      for (int r = 0; r < 4; ++r) {
        size_t idx = (size_t)(tb + mt * 16 + quad * 4 + r) * DEMB + e;
        y_out[idx] = xreg[r] + acc2[r];
      }
    }
    // UV = Ytile @ Wsw^T  (wave's 16 channels x 32 tokens)
    floatx4 acc[2];
    acc[0] = fzero; acc[1] = fzero;
#pragma unroll
    for (int kt = 0; kt < 8; ++kt) {
      short8 a0 = *(const short8*)&Ylds[cur][(l15)      * YSTR + kt * 32 + quad * 8];
      short8 a1 = *(const short8*)&Ylds[cur][(16 + l15) * YSTR + kt * 32 + quad * 8];
      acc[0] = MFMA_BF16(a0, b1[kt], acc[0], 0, 0, 0);
      acc[1] = MFMA_BF16(a1, b1[kt], acc[1], 0, 0, 0);
    }
    // writeback as bf16 UV^T[c][t]: packed b64
#pragma unroll
    for (int m2 = 0; m2 < 2; ++m2) {
      short4_t p4;
#pragma unroll
      for (int r = 0; r < 4; ++r) p4[r] = f2bf(acc[m2][r]);
      int c  = wave * 16 + l15;
      int t0 = m2 * 16 + quad * 4;
      *(short4_t*)&UVT[c * TSTR + t0] = p4;
    }
    __syncthreads();   // barrier B

    // ================= region RY =================
    // issue x loads for THIS tile (used in next RX's epilogue)
    {
      const float* xb = x + (size_t)(tok0 + it * TILE_T) * DEMB + eb * 16 + l15;
#pragma unroll
      for (int r = 0; r < 4; ++r)
        xreg[r] = xb[(mt * 16 + quad * 4 + r) * DEMB];
    }
    // h = u * silu(v) -> Hlds  (4 tokens per thread)
    {
      int d  = tid & 63;
      int t0 = (tid >> 6) * 4;
      short4_t u4 = *(const short4_t*)&UVT[d * TSTR + t0];
      short4_t v4 = *(const short4_t*)&UVT[(64 + d) * TSTR + t0];
#pragma unroll
      for (int j = 0; j < 4; ++j) {
        float h = bf2f(u4[j]) * silu_f(bf2f(v4[j]));
        Hlds[(t0 + j) * HSTR + d] = f2bf(h);
      }
    }
    // ao += u^T v  (wave's d-block x 2 e-tiles)
    {
      short8 a3 = *(const short8*)&UVT[(db * 16 + l15) * TSTR + quad * 8];
#pragma unroll
      for (int i = 0; i < 2; ++i) {
        short8 b3 = *(const short8*)&UVT[(64 + (e0 + i) * 16 + l15) * TSTR + quad * 8];
        ao_acc[i] = MFMA_BF16(a3, b3, ao_acc[i], 0, 0, 0);
      }
    }
    // pack prefetched y -> other Y buffer
    if (it + 1 < ITERS) {
#pragma unroll
      for (int rep = 0; rep < 4; ++rep) {
        int i = tid + rep * 512;
        int tok = i >> 6;
        int col = (i & 63) * 4;
        float4 f = yreg[rep];
        short4_t p4 = { f2bf(f.x), f2bf(f.y), f2bf(f.z), f2bf(f.w) };
        *(short4_t*)&Ylds[1 - cur][tok * YSTR + col] = p4;
      }
    }
    __syncthreads();   // barrier A (next iter)
  }

  // ---- final epilogue (tile ITERS-1) ----
  {
    const int tb = tok0 + (ITERS - 1) * TILE_T;
    floatx4 acc2 = fzero;
#pragma unroll
    for (int kt = 0; kt < 2; ++kt) {
      short8 a2 = *(const short8*)&Hlds[(mt * 16 + l15) * HSTR + kt * 32 + quad * 8];
      acc2 = MFMA_BF16(a2, b2[kt], acc2, 0, 0, 0);
    }
    int e = eb * 16 + l15;
#pragma unroll
    for (int r = 0; r < 4; ++r) {
      size_t idx = (size_t)(tb + mt * 16 + quad * 4 + r) * DEMB + e;
      y_out[idx] = xreg[r] + acc2[r];
    }
  }

  // ---- flush ao partials ----
  float* dst = ao_copies + (blockIdx.x & (AO_COPIES - 1)) * 4096;
#pragma unroll
  for (int i = 0; i < 2; ++i)
#pragma unroll
    for (int r = 0; r < 4; ++r) {
      int d = db * 16 + quad * 4 + r;
      int e = (e0 + i) * 16 + l15;
      atomicAdd(&dst[d * 64 + e], ao_acc[i][r]);
    }
}

// ========== K3 fused: ao finalize + weight updates + final scale =======
// 21 blocks x 256 threads (4 waves = 4 rids each; 84 rids total).
// Phase 0: every block redundantly reduces ao_copies (262 KB, L2-hot) and
//          builds the rms-normed aoT in LDS -- replaces the old 1-block k2.
// Phase 1: per-wave k3 update-candidate GEMMs; vals held in registers.
// Phase 2: 84-wave device-scope counter barrier (21 blocks trivially
//          co-resident), then each wave reads the global sums and writes
//          its own vals * scale -- replaces the old k4 launch. The only
//          cross-block data are atomics (sums, cnt): XCD-coherence safe.
__global__ __launch_bounds__(256) void k3_fused(
    const float* __restrict__ w_qkv, const float* __restrict__ w_sw,
    const float* __restrict__ w_out, const float* __restrict__ out_w,
    const float* __restrict__ ao_copies, const float* __restrict__ tao,
    float* __restrict__ out, float* __restrict__ sums,
    unsigned* __restrict__ cnt)
{
  __shared__ float aoFT[64 * 65];   // [e][d], pad 65
  __shared__ float ssPart[256];
  __shared__ float scRow[64];
  __shared__ __align__(16) short Nlds[4][16 * 72];
  const int tid = threadIdx.x;

  // ---- phase 0: finalize ao (redundant per block, parallel across 21) ----
#pragma unroll
  for (int k = 0; k < 16; ++k) {
    int idx = k * 256 + tid;          // = d*64 + e, coalesced
    float v = 0.f;
#pragma unroll
    for (int c = 0; c < AO_COPIES; ++c) v += ao_copies[c * 4096 + idx];
    v *= (1.0f / 64.0f);              // /B * n_embd^-0.5
    int d = idx >> 6, e = idx & 63;
    aoFT[e * 65 + d] = v;
  }
  __syncthreads();
  {
    int d = tid >> 2, q = tid & 3;
    float ssp = 0.f;
#pragma unroll
    for (int e2 = 0; e2 < 16; ++e2) {
      float v = aoFT[(q * 16 + e2) * 65 + d];
      ssp += v * v;
    }
    ssPart[tid] = ssp;
  }
  __syncthreads();
  if (tid < 64) {
    float ss = ssPart[tid * 4] + ssPart[tid * 4 + 1] +
               ssPart[tid * 4 + 2] + ssPart[tid * 4 + 3];
    scRow[tid] = rsqrtf(ss * (1.0f / 64.0f) + 1.1920929e-07f);
  }
  __syncthreads();

  const int lane = tid & 63;
  const int wave = tid >> 6;
  const int l15  = lane & 15;
  const int quad = lane >> 4;
  const int rid  = blockIdx.x * 4 + wave;   // [0, 84)
  const floatx4 fzero = {0.f, 0.f, 0.f, 0.f};

  // bf[kt][nt] lanewise: e = nt*16+l15, d = kt*32+quad*8+j
  short8 bf[2][4];
#pragma unroll
  for (int kt = 0; kt < 2; ++kt)
#pragma unroll
    for (int nt = 0; nt < 4; ++nt) {
      short8 f;
#pragma unroll
      for (int j = 0; j < 8; ++j) {
        int d = kt * 32 + quad * 8 + j;
        f[j] = f2bf(aoFT[(nt * 16 + l15) * 65 + d] * scRow[d]);
      }
      bf[kt][nt] = f;
    }

  short8 af[2];
  if (rid < 48) {
    const float* wr = w_qkv + (size_t)(rid * 16 + l15) * 64;
#pragma unroll
    for (int kt = 0; kt < 2; ++kt) {
      const float* p = wr + kt * 32 + quad * 8;
      short8 f;
#pragma unroll
      for (int j = 0; j < 8; ++j) f[j] = f2bf(p[j]);
      af[kt] = f;
    }
  } else if (rid < 80) {
    int p0 = (rid - 48) * 16;
#pragma unroll
    for (int kt = 0; kt < 2; ++kt) {
      short8 f;
#pragma unroll
      for (int j = 0; j < 8; ++j) {
        int a = kt * 32 + quad * 8 + j;
        f[j] = f2bf(w_sw[a * 512 + p0 + l15]);
      }
      af[kt] = f;
    }
  } else {
    const float* wr = w_out + (size_t)((rid - 80) * 16 + l15) * 64;
#pragma unroll
    for (int kt = 0; kt < 2; ++kt) {
      const float* p = wr + kt * 32 + quad * 8;
      short8 f;
#pragma unroll
      for (int j = 0; j < 8; ++j) f[j] = f2bf(p[j]);
      af[kt] = f;
    }
  }

  floatx4 acc[4];
#pragma unroll
  for (int nt = 0; nt < 4; ++nt) acc[nt] = fzero;
#pragma unroll
  for (int kt = 0; kt < 2; ++kt)
#pragma unroll
    for (int nt = 0; nt < 4; ++nt)
      acc[nt] = MFMA_BF16(af[kt], bf[kt][nt], acc[nt], 0, 0, 0);
#pragma unroll
  for (int nt = 0; nt < 4; ++nt)
#pragma unroll
    for (int r = 0; r < 4; ++r)
      Nlds[wave][(quad * 4 + r) * 72 + nt * 16 + l15] = f2bf(silu_f(acc[nt][r]));
  __syncthreads();

  float s1 = 0.f, s2 = 0.f;
  int matrix;
  float vals[16];

  if (rid < 48 || rid >= 80) {
    matrix = (rid < 48) ? 0 : 2;
    short8 a2[2];
#pragma unroll
    for (int kt = 0; kt < 2; ++kt)
      a2[kt] = *(const short8*)&Nlds[wave][l15 * 72 + kt * 32 + quad * 8];
    short8 b2w[2][4];
#pragma unroll
    for (int nt = 0; nt < 4; ++nt) {
      const float* wr = out_w + (size_t)(nt * 16 + l15) * 64;
#pragma unroll
      for (int kt = 0; kt < 2; ++kt) {
        const float* p = wr + kt * 32 + quad * 8;
        short8 f;
#pragma unroll
        for (int j = 0; j < 8; ++j) f[j] = f2bf(p[j]);
        b2w[kt][nt] = f;
      }
    }
    floatx4 acc2[4];
#pragma unroll
    for (int nt = 0; nt < 4; ++nt) acc2[nt] = fzero;
#pragma unroll
    for (int kt = 0; kt < 2; ++kt)
#pragma unroll
      for (int nt = 0; nt < 4; ++nt)
        acc2[nt] = MFMA_BF16(a2[kt], b2w[kt][nt], acc2[nt], 0, 0, 0);

    const float* Wsrc = (rid < 48) ? w_qkv : w_out;
    int base_row = (rid < 48) ? rid * 16 : (rid - 80) * 16;
#pragma unroll
    for (int nt = 0; nt < 4; ++nt)
#pragma unroll
      for (int r = 0; r < 4; ++r) {
        int row = base_row + quad * 4 + r;
        int col = nt * 16 + l15;
        float val = Wsrc[row * 64 + col] + acc2[nt][r];
        vals[nt * 4 + r] = val;
        s1 += val; s2 += val * val;
      }
  } else {
    matrix = 1;
    int p0 = (rid - 48) * 16;
    short8 b2s[2];
#pragma unroll
    for (int kt = 0; kt < 2; ++kt)
      b2s[kt] = *(const short8*)&Nlds[wave][l15 * 72 + kt * 32 + quad * 8];
    short8 a2w[4][2];
#pragma unroll
    for (int mt = 0; mt < 4; ++mt) {
      const float* wr = out_w + (size_t)(mt * 16 + l15) * 64;
#pragma unroll
      for (int kt = 0; kt < 2; ++kt) {
        const float* p = wr + kt * 32 + quad * 8;
        short8 f;
#pragma unroll
        for (int j = 0; j < 8; ++j) f[j] = f2bf(p[j]);
        a2w[mt][kt] = f;
      }
    }
    floatx4 acc2[4];
#pragma unroll
    for (int mt = 0; mt < 4; ++mt) acc2[mt] = fzero;
#pragma unroll
    for (int mt = 0; mt < 4; ++mt)
#pragma unroll
      for (int kt = 0; kt < 2; ++kt)
        acc2[mt] = MFMA_BF16(a2w[mt][kt], b2s[kt], acc2[mt], 0, 0, 0);
#pragma unroll
    for (int mt = 0; mt < 4; ++mt)
#pragma unroll
      for (int r = 0; r < 4; ++r) {
        int a = mt * 16 + quad * 4 + r;
        float val = w_sw[a * 512 + p0 + l15] + acc2[mt][r];
        vals[mt * 4 + r] = val;
        s1 += val; s2 += val * val;
      }
  }

#pragma unroll
  for (int off = 32; off > 0; off >>= 1) {
    s1 += __shfl_down(s1, off);
    s2 += __shfl_down(s2, off);
  }
  if (lane == 0) {
    atomicAdd(&sums[matrix * 2],     s1);
    atomicAdd(&sums[matrix * 2 + 1], s2);
    // release-publish this wave's contribution
    __hip_atomic_fetch_add(cnt, 1u, __ATOMIC_RELEASE, __HIP_MEMORY_SCOPE_AGENT);
  }
  // all lanes spin until all 84 waves have published (acquire orders the
  // subsequent sums loads); 21 blocks on 256 CUs are always co-resident
  while (__hip_atomic_load(cnt, __ATOMIC_ACQUIRE, __HIP_MEMORY_SCOPE_AGENT) < 84u) {
    __builtin_amdgcn_s_sleep(1);
  }

  float ssum = __hip_atomic_load(&sums[matrix * 2],
                                 __ATOMIC_RELAXED, __HIP_MEMORY_SCOPE_AGENT);
  float ssq  = __hip_atomic_load(&sums[matrix * 2 + 1],
                                 __ATOMIC_RELAXED, __HIP_MEMORY_SCOPE_AGENT);
  float N    = (matrix == 0) ? 49152.f : (matrix == 1) ? 32768.f : 4096.f;
  float tstd = (matrix == 0) ? 0.125f : 0.0625f;
  float mean = ssum / N;
  float var  = (ssq - N * mean * mean) / (N - 1.f);
  float sd   = sqrtf(fmaxf(var, 0.f));
  float g    = fminf(fmaxf(fabsf(tao[matrix]), 1e-8f), 1.0f);
  float scale = g * tstd / (sd + 1e-8f);

  if (rid < 48 || rid >= 80) {
    int base_row = (rid < 48) ? rid * 16 : (rid - 80) * 16;
    int off2     = (rid < 48) ? OFF_QKV : OFF_WO;
#pragma unroll
    for (int nt = 0; nt < 4; ++nt)
#pragma unroll
      for (int r = 0; r < 4; ++r) {
        int row = base_row + quad * 4 + r;
        int col = nt * 16 + l15;
        out[off2 + row * 64 + col] = vals[nt * 4 + r] * scale;
      }
  } else {
    int p0 = (rid - 48) * 16;
#pragma unroll
    for (int mt = 0; mt < 4; ++mt)
#pragma unroll
      for (int r = 0; r < 4; ++r) {
        int a = mt * 16 + quad * 4 + r;
        out[OFF_SW + a * 512 + p0 + l15] = vals[mt * 4 + r] * scale;
      }
  }
}

extern "C" void kernel_launch(void* const* d_in, const int* in_sizes, int n_in,
                              void* d_out, int out_size, void* d_ws, size_t ws_size,
                              hipStream_t stream) {
  const float* x     = (const float*)d_in[0];
  const float* y     = (const float*)d_in[1];
  const float* w_qkv = (const float*)d_in[2];
  const float* w_sw  = (const float*)d_in[3];
  const float* w_out = (const float*)d_in[4];
  const float* out_w = (const float*)d_in[5];
  const float* tao   = (const float*)d_in[6];
  float* out = (float*)d_out;
  float* ws  = (float*)d_ws;

  float* ao_copies = ws;
  float* sums      = ws + WS_SUMS;
  unsigned* cnt    = (unsigned*)(ws + WS_SUMS + 7);

  hipMemsetAsync(d_ws, 0, (WS_SUMS + 8) * sizeof(float), stream);
  k1_main<<<dim3(NBLK1), dim3(512), 0, stream>>>(x, y, w_sw, w_out, out, ao_copies);
  k3_fused<<<dim3(21), dim3(256), 0, stream>>>(w_qkv, w_sw, w_out, out_w,
                                               ao_copies, tao, out, sums, cnt);
}